// Round 1
// baseline (13.299 us; speedup 1.0000x reference)
//
#include <hip/hip_runtime.h>
#include <math.h>

__device__ __forceinline__ float sigm(float x) { return 1.0f / (1.0f + __expf(-x)); }

// Encoder GRU single step with h0 = 0, input-size 1, hidden 4.
// gi = x*Wih + bih ; gh = bhh (h0==0) ; r=sig(i_r+h_r), z=sig(i_z+h_z),
// n=tanh(i_n + r*h_n) ; h = (1-z)*n
__device__ __forceinline__ void enc_step(float xb, const float* __restrict__ Wih,
                                         const float* __restrict__ bih,
                                         const float* __restrict__ bhh, float h[4]) {
#pragma unroll
    for (int j = 0; j < 4; ++j) {
        float ir = fmaf(xb, Wih[j],     bih[j])     + bhh[j];
        float iz = fmaf(xb, Wih[4 + j], bih[4 + j]) + bhh[4 + j];
        float in_ = fmaf(xb, Wih[8 + j], bih[8 + j]);
        float hn  = bhh[8 + j];
        float r = sigm(ir);
        float z = sigm(iz);
        float n = tanhf(fmaf(r, hn, in_));
        h[j] = (1.0f - z) * n;
    }
}

// Kernel A: every block redundantly computes the encoder into LDS (1000-vec),
// then each of the 4 waves computes one fc1 output row (1000-MAC dot + ReLU).
// Grid = 128 blocks -> 512 outputs.
__global__ __launch_bounds__(256) void kA(const float* __restrict__ x,
                                          const float* __restrict__ eWih,
                                          const float* __restrict__ ebih,
                                          const float* __restrict__ ebhh,
                                          const float* __restrict__ fc1W,
                                          const float* __restrict__ fc1b,
                                          float* __restrict__ hid) {
    __shared__ float stacked[1000];
    const int t = threadIdx.x;
    if (t < 250) {
        float h[4];
        enc_step(x[t], eWih, ebih, ebhh, h);
        stacked[t * 4 + 0] = h[0];
        stacked[t * 4 + 1] = h[1];
        stacked[t * 4 + 2] = h[2];
        stacked[t * 4 + 3] = h[3];
    }
    __syncthreads();
    const int wave = t >> 6, lane = t & 63;
    const int j = blockIdx.x * 4 + wave;   // < 512 always
    const float* wrow = fc1W + j * 1000;
    float s = 0.0f;
    for (int k = lane; k < 1000; k += 64) s = fmaf(stacked[k], wrow[k], s);
#pragma unroll
    for (int m = 32; m >= 1; m >>= 1) s += __shfl_xor(s, m, 64);
    if (lane == 0) hid[j] = fmaxf(s + fc1b[j], 0.0f);
}

// Kernel B: one wave per batch element i: fc2 row dot (512 MACs) -> hn[i],
// then fused decoder GRU step (recomputing encoder y[i] locally).
// Grid = 63 blocks x 4 waves -> 252 waves (2 idle).
__global__ __launch_bounds__(256) void kB(const float* __restrict__ x,
                                          const float* __restrict__ eWih,
                                          const float* __restrict__ ebih,
                                          const float* __restrict__ ebhh,
                                          const float* __restrict__ hid,
                                          const float* __restrict__ fc2W,
                                          const float* __restrict__ fc2b,
                                          const float* __restrict__ dWih,
                                          const float* __restrict__ dWhh,
                                          const float* __restrict__ dbih,
                                          const float* __restrict__ dbhh,
                                          float* __restrict__ out) {
    const int t = threadIdx.x;
    const int wave = t >> 6, lane = t & 63;
    const int i = blockIdx.x * 4 + wave;
    if (i >= 250) return;
    const float* wrow = fc2W + i * 512;
    float s = 0.0f;
#pragma unroll
    for (int q = 0; q < 8; ++q) {
        const int k = lane + q * 64;
        s = fmaf(hid[k], wrow[k], s);
    }
#pragma unroll
    for (int m = 32; m >= 1; m >>= 1) s += __shfl_xor(s, m, 64);
    const float hn_i = s + fc2b[i];
    if (lane == 0) {
        float y[4];
        enc_step(x[i], eWih, ebih, ebhh, y);
        float gi[3];
#pragma unroll
        for (int g = 0; g < 3; ++g) {
            gi[g] = fmaf(y[0], dWih[g * 4 + 0],
                    fmaf(y[1], dWih[g * 4 + 1],
                    fmaf(y[2], dWih[g * 4 + 2],
                    fmaf(y[3], dWih[g * 4 + 3], dbih[g]))));
        }
        const float gh0 = fmaf(hn_i, dWhh[0], dbhh[0]);
        const float gh1 = fmaf(hn_i, dWhh[1], dbhh[1]);
        const float gh2 = fmaf(hn_i, dWhh[2], dbhh[2]);
        const float r = sigm(gi[0] + gh0);
        const float z = sigm(gi[1] + gh1);
        const float n = tanhf(fmaf(r, gh2, gi[2]));
        out[i] = fmaf(z, hn_i, (1.0f - z) * n);
    }
}

extern "C" void kernel_launch(void* const* d_in, const int* in_sizes, int n_in,
                              void* d_out, int out_size, void* d_ws, size_t ws_size,
                              hipStream_t stream) {
    const float* x     = (const float*)d_in[0];
    const float* eWih  = (const float*)d_in[1];
    // d_in[2] = enc_Whh — unused (h0 == 0 makes the Whh term vanish)
    const float* ebih  = (const float*)d_in[3];
    const float* ebhh  = (const float*)d_in[4];
    const float* fc1W  = (const float*)d_in[5];
    const float* fc1b  = (const float*)d_in[6];
    const float* fc2W  = (const float*)d_in[7];
    const float* fc2b  = (const float*)d_in[8];
    const float* dWih  = (const float*)d_in[9];
    const float* dWhh  = (const float*)d_in[10];
    const float* dbih  = (const float*)d_in[11];
    const float* dbhh  = (const float*)d_in[12];
    float* out = (float*)d_out;
    float* hid = (float*)d_ws;   // 512 floats

    kA<<<128, 256, 0, stream>>>(x, eWih, ebih, ebhh, fc1W, fc1b, hid);
    kB<<<63, 256, 0, stream>>>(x, eWih, ebih, ebhh, hid, fc2W, fc2b,
                               dWih, dWhh, dbih, dbhh, out);
}